// Round 1
// baseline (201.608 us; speedup 1.0000x reference)
//
#include <hip/hip_runtime.h>
#include <math.h>

static constexpr int kB  = 16;
static constexpr int kT  = 15;
static constexpr int kH  = 480;
static constexpr int kW  = 640;
static constexpr int kCH = 16;
static constexpr int kP  = 8;
static constexpr int kN  = kB * 16 * 16;   // 4096 sequences
static constexpr float kEPS = 1e-5f;

__device__ __forceinline__ float gelu_exact(float v) {
    return 0.5f * v * (1.0f + erff(v * 0.7071067811865476f));
}

// ---------------------------------------------------------------------------
// K1: 30x40 block-mean downsample. One block per (b,t,i). Reads 295 MB.
// threads 0..159 each own one float4 column (40 cols = 10 float4 per k-block),
// sum 30 rows (coalesced 2560B rows), then 16 threads reduce 10 col-sums each.
// ---------------------------------------------------------------------------
__global__ __launch_bounds__(256) void k_down(const float* __restrict__ x,
                                              float* __restrict__ seq) {
    int blk = blockIdx.x;          // (b*kT + t)*16 + i
    int i  = blk & 15;
    int bt = blk >> 4;             // b*kT + t
    int t  = bt % kT;
    int b  = bt / kT;
    const float4* src = (const float4*)(x + ((size_t)bt * kH + (size_t)i * 30) * kW);
    __shared__ float colsum[160];
    int tid = threadIdx.x;
    if (tid < 160) {
        float acc = 0.f;
        #pragma unroll
        for (int r = 0; r < 30; ++r) {
            float4 v = src[r * 160 + tid];
            acc += (v.x + v.y) + (v.z + v.w);
        }
        colsum[tid] = acc;
    }
    __syncthreads();
    if (tid < 16) {
        float s = 0.f;
        #pragma unroll
        for (int j = 0; j < 10; ++j) s += colsum[tid * 10 + j];
        s *= (1.0f / 1200.0f);
        seq[t * kN + b * 256 + i * 16 + tid] = s;   // [t][n] layout, coalesced K2 reads
    }
}

// ---------------------------------------------------------------------------
// K2: per-sequence SSM scan + last-step MLP head. One thread per sequence.
// LN1 of an affine-in-s input collapses to closed form; Bu[p] collapses to
// r*(s*P1[p]+P0[p])+Pb[p]. Only t=T-1 feeds the output head.
// ---------------------------------------------------------------------------
__global__ __launch_bounds__(256, 1) void k_ssm(
    const float* __restrict__ seq,
    const float* __restrict__ w_in, const float* __restrict__ b_in,
    const float* __restrict__ ln1_g, const float* __restrict__ ln1_b,
    const float* __restrict__ Lam_re, const float* __restrict__ Lam_im,
    const float* __restrict__ Bre, const float* __restrict__ Bim,
    const float* __restrict__ Cre, const float* __restrict__ Cim,
    const float* __restrict__ Dv, const float* __restrict__ log_step,
    const float* __restrict__ ln2_g, const float* __restrict__ ln2_b,
    const float* __restrict__ w_enc, const float* __restrict__ w_dec,
    const float* __restrict__ w_out, const float* __restrict__ b_out,
    float* __restrict__ yd)
{
    const int n = blockIdx.x * 256 + threadIdx.x;   // [0,4096)

    // LN1 closed-form stats
    float av[kCH], dvv[kCH], g1[kCH], b1[kCH];
    float mw = 0.f, mb = 0.f;
    #pragma unroll
    for (int c = 0; c < kCH; ++c) {
        av[c] = w_in[c]; dvv[c] = b_in[c];
        g1[c] = ln1_g[c]; b1[c] = ln1_b[c];
        mw += av[c]; mb += dvv[c];
    }
    mw *= (1.f / kCH); mb *= (1.f / kCH);
    float Saa = 0.f, Sad = 0.f, Sdd = 0.f;
    #pragma unroll
    for (int c = 0; c < kCH; ++c) {
        av[c] -= mw; dvv[c] -= mb;
        Saa += av[c] * av[c];
        Sad += av[c] * dvv[c];
        Sdd += dvv[c] * dvv[c];
    }
    Saa *= (1.f / kCH); Sad *= (1.f / kCH); Sdd *= (1.f / kCH);

    // per-pole discretization + projected input vectors
    float Lbr[kP], Lbi[kP];
    float P1r[kP], P1i[kP], P0r[kP], P0i[kP], Pbr[kP], Pbi[kP];
    float msk[kP];
    #pragma unroll
    for (int p = 0; p < kP; ++p) {
        float st  = expf(log_step[p]);
        float lre = Lam_re[p], lim = Lam_im[p];
        float eL  = expf(lre * st);
        float lbr = eL * cosf(lim * st), lbi = eL * sinf(lim * st);
        Lbr[p] = lbr; Lbi[p] = lbi;
        float inv = 1.f / (lre * lre + lim * lim);
        float nr = lbr - 1.f, ni = lbi;
        float qr = (nr * lre + ni * lim) * inv;    // (Lam_bar-1)/Lam
        float qi = (ni * lre - nr * lim) * inv;
        float s1r = 0.f, s1i = 0.f, s0r = 0.f, s0i = 0.f, sbr = 0.f, sbi = 0.f;
        #pragma unroll
        for (int c = 0; c < kCH; ++c) {
            float br = Bre[p * kCH + c], bi = Bim[p * kCH + c];
            float a1 = av[c]  * g1[c];
            float a0 = dvv[c] * g1[c];
            s1r += a1 * br;   s1i += a1 * bi;
            s0r += a0 * br;   s0i += a0 * bi;
            sbr += b1[c] * br; sbi += b1[c] * bi;
        }
        P1r[p] = qr * s1r - qi * s1i;  P1i[p] = qr * s1i + qi * s1r;
        P0r[p] = qr * s0r - qi * s0i;  P0i[p] = qr * s0i + qi * s0r;
        Pbr[p] = qr * sbr - qi * sbi;  Pbi[p] = qr * sbi + qi * sbr;
        float freq = st * fabsf(lim) * 0.15915494309189535f;  // /(2*pi)
        msk[p] = (freq < 0.25f) ? 1.f : 0.f;
    }

    float xr[kP], xi[kP];
    #pragma unroll
    for (int p = 0; p < kP; ++p) { xr[p] = 0.f; xi[p] = 0.f; }

    float s_last = 0.f, r_last = 0.f;
    for (int t = 0; t < kT; ++t) {
        float s = seq[t * kN + n];
        float var = (s * s) * Saa + 2.f * s * Sad + Sdd;
        float r = rsqrtf(var + kEPS);
        float be = r * s;
        #pragma unroll
        for (int p = 0; p < kP; ++p) {
            float bur = be * P1r[p] + r * P0r[p] + Pbr[p];
            float bui = be * P1i[p] + r * P0i[p] + Pbi[p];
            float nxr = Lbr[p] * xr[p] - Lbi[p] * xi[p] + bur;
            float nxi = Lbr[p] * xi[p] + Lbi[p] * xr[p] + bui;
            xr[p] = nxr; xi[p] = nxi;
        }
        s_last = s; r_last = r;
    }

    // last-step head
    float fx[kCH];
    #pragma unroll
    for (int c = 0; c < kCH; ++c)
        fx[c] = (s_last * av[c] + dvv[c]) * r_last * g1[c] + b1[c];

    float xmr[kP], xmi[kP];
    #pragma unroll
    for (int p = 0; p < kP; ++p) { xmr[p] = xr[p] * msk[p]; xmi[p] = xi[p] * msk[p]; }

    float x1[kCH];
    float m1 = 0.f;
    #pragma unroll
    for (int c = 0; c < kCH; ++c) {
        float ys = fx[c] * Dv[c];
        #pragma unroll
        for (int p = 0; p < kP; ++p)
            ys += xmr[p] * Cre[c * kP + p] - xmi[p] * Cim[c * kP + p];
        x1[c] = gelu_exact(ys) + fx[c];
        m1 += x1[c];
    }
    m1 *= (1.f / kCH);
    float v1 = 0.f;
    #pragma unroll
    for (int c = 0; c < kCH; ++c) { float d = x1[c] - m1; v1 += d * d; }
    v1 *= (1.f / kCH);
    float rs2 = rsqrtf(v1 + kEPS);
    float fx2[kCH];
    #pragma unroll
    for (int c = 0; c < kCH; ++c)
        fx2[c] = (x1[c] - m1) * rs2 * ln2_g[c] + ln2_b[c];

    float hgate[kCH];
    #pragma unroll
    for (int j = 0; j < kCH; ++j) {
        float e1 = 0.f, e2 = 0.f;
        #pragma unroll
        for (int c = 0; c < kCH; ++c) {
            e1 += fx2[c] * w_enc[j * kCH + c];
            e2 += fx2[c] * w_enc[(kCH + j) * kCH + c];
        }
        hgate[j] = e1 * gelu_exact(e2);
    }
    float x2v[kCH];
    #pragma unroll
    for (int c = 0; c < kCH; ++c) {
        float acc = fx2[c];
        #pragma unroll
        for (int j = 0; j < kCH; ++j) acc += hgate[j] * w_dec[c * kCH + j];
        x2v[c] = acc;
    }
    int b = n >> 8, rem = n & 255;
    #pragma unroll
    for (int c = 0; c < kCH; ++c) {
        float acc = b_out[c];
        #pragma unroll
        for (int j = 0; j < kCH; ++j) acc += x2v[j] * w_out[c * kCH + j];
        yd[(b * kCH + c) * 256 + rem] = acc;   // yd[b][c][i][k] layout
    }
}

// ---------------------------------------------------------------------------
// K3: bilinear upsample 16x16 -> 480x640 per (b,ch). One block per (b,ch) =
// 256 blocks (1/CU). Source tile in LDS (reads are wave-broadcast), float4
// coalesced stores. Writes 315 MB.
// ---------------------------------------------------------------------------
__global__ __launch_bounds__(256) void k_up(const float* __restrict__ yd,
                                            float* __restrict__ out) {
    const int bc = blockIdx.x;              // b*16 + c
    __shared__ float g[256];                // 16x16 source tile
    g[threadIdx.x] = yd[bc * 256 + threadIdx.x];
    __syncthreads();
    float4* dst = (float4*)(out + (size_t)bc * (kH * kW));
    const float sy = 15.0f / 479.0f;
    const float sx = 15.0f / 639.0f;
    for (int it = 0; it < 300; ++it) {
        int f4 = it * 256 + (int)threadIdx.x;   // [0, 480*160)
        int ho = f4 / 160;
        int w4 = f4 - ho * 160;
        float ry = (float)ho * sy;
        int y0 = (int)ry;
        float wy = ry - (float)y0;
        int y1 = min(y0 + 1, 15);
        const float* r0 = &g[y0 * 16];
        const float* r1 = &g[y1 * 16];
        float4 res;
        #pragma unroll
        for (int j = 0; j < 4; ++j) {
            int wo = w4 * 4 + j;
            float rx = (float)wo * sx;
            int x0 = (int)rx;
            float wx = rx - (float)x0;
            int x1 = min(x0 + 1, 15);
            float top = r0[x0] + (r0[x1] - r0[x0]) * wx;
            float bot = r1[x0] + (r1[x1] - r1[x0]) * wx;
            ((float*)&res)[j] = top + (bot - top) * wy;
        }
        dst[f4] = res;
    }
}

extern "C" void kernel_launch(void* const* d_in, const int* in_sizes, int n_in,
                              void* d_out, int out_size, void* d_ws, size_t ws_size,
                              hipStream_t stream) {
    const float* x     = (const float*)d_in[0];
    const float* w_in  = (const float*)d_in[1];
    const float* b_in  = (const float*)d_in[2];
    const float* ln1_g = (const float*)d_in[3];
    const float* ln1_b = (const float*)d_in[4];
    const float* Lre   = (const float*)d_in[5];
    const float* Lim   = (const float*)d_in[6];
    const float* Bre   = (const float*)d_in[7];
    const float* Bim   = (const float*)d_in[8];
    const float* Cre   = (const float*)d_in[9];
    const float* Cim   = (const float*)d_in[10];
    const float* Dv    = (const float*)d_in[11];
    const float* lstep = (const float*)d_in[12];
    const float* ln2_g = (const float*)d_in[13];
    const float* ln2_b = (const float*)d_in[14];
    const float* w_enc = (const float*)d_in[15];
    const float* w_dec = (const float*)d_in[16];
    const float* w_out = (const float*)d_in[17];
    const float* b_out = (const float*)d_in[18];

    float* seq = (float*)d_ws;          // kT*kN     = 61440 floats
    float* yd  = seq + kT * kN;         // kB*kCH*256 = 65536 floats
    float* out = (float*)d_out;

    k_down<<<kB * kT * 16, 256, 0, stream>>>(x, seq);
    k_ssm<<<kN / 256, 256, 0, stream>>>(seq, w_in, b_in, ln1_g, ln1_b, Lre, Lim,
                                        Bre, Bim, Cre, Cim, Dv, lstep, ln2_g, ln2_b,
                                        w_enc, w_dec, w_out, b_out, yd);
    k_up<<<kB * kCH, 256, 0, stream>>>(yd, out);
}

// Round 2
// 180.254 us; speedup vs baseline: 1.1185x; 1.1185x over previous
//
#include <hip/hip_runtime.h>
#include <math.h>

static constexpr int kB  = 16;
static constexpr int kT  = 15;
static constexpr int kH  = 480;
static constexpr int kW  = 640;
static constexpr int kCH = 16;
static constexpr int kP  = 8;
static constexpr int kN  = kB * 16 * 16;   // 4096 sequences
static constexpr float kEPS = 1e-5f;

__device__ __forceinline__ float gelu_exact(float v) {
    return 0.5f * v * (1.0f + erff(v * 0.7071067811865476f));
}

// ---------------------------------------------------------------------------
// K1: 30x40 block-mean downsample. One block per (b,t,i)-strip (30 rows).
// 320 threads: tid -> (rhalf = tid/160, col4 = tid%160); each sums 15 rows of
// one float4 column (rows are 2560B contiguous, fully coalesced). Then 16
// threads reduce 2x10 col-sums each into seq[t][n].
// ---------------------------------------------------------------------------
__global__ __launch_bounds__(320) void k_down(const float* __restrict__ x,
                                              float* __restrict__ seq) {
    int blk = blockIdx.x;          // (b*kT + t)*16 + i
    int i  = blk & 15;
    int bt = blk >> 4;             // b*kT + t
    int t  = bt % kT;
    int b  = bt / kT;
    const float4* src = (const float4*)(x + ((size_t)bt * kH + (size_t)i * 30) * kW);
    __shared__ float colsum[320];
    int tid = threadIdx.x;
    int rhalf = tid / 160;
    int col4  = tid - rhalf * 160;
    const float4* s0 = src + (size_t)(rhalf * 15) * 160 + col4;
    float acc = 0.f;
    #pragma unroll
    for (int r = 0; r < 15; ++r) {
        float4 v = s0[r * 160];
        acc += (v.x + v.y) + (v.z + v.w);
    }
    colsum[tid] = acc;
    __syncthreads();
    if (tid < 16) {
        float s = 0.f;
        #pragma unroll
        for (int j = 0; j < 10; ++j)
            s += colsum[tid * 10 + j] + colsum[160 + tid * 10 + j];
        s *= (1.0f / 1200.0f);
        seq[t * kN + b * 256 + i * 16 + tid] = s;   // [t][n] layout, coalesced K2 reads
    }
}

// ---------------------------------------------------------------------------
// K2: per-sequence SSM scan + last-step MLP head. One thread per sequence.
// LN1 of an affine-in-s input collapses to closed form; Bu[p] collapses to
// r*(s*P1[p]+P0[p])+Pb[p]. Only t=T-1 feeds the output head.
// 64 blocks x 64 threads spreads the serial scans across CUs.
// ---------------------------------------------------------------------------
__global__ __launch_bounds__(64, 1) void k_ssm(
    const float* __restrict__ seq,
    const float* __restrict__ w_in, const float* __restrict__ b_in,
    const float* __restrict__ ln1_g, const float* __restrict__ ln1_b,
    const float* __restrict__ Lam_re, const float* __restrict__ Lam_im,
    const float* __restrict__ Bre, const float* __restrict__ Bim,
    const float* __restrict__ Cre, const float* __restrict__ Cim,
    const float* __restrict__ Dv, const float* __restrict__ log_step,
    const float* __restrict__ ln2_g, const float* __restrict__ ln2_b,
    const float* __restrict__ w_enc, const float* __restrict__ w_dec,
    const float* __restrict__ w_out, const float* __restrict__ b_out,
    float* __restrict__ yd)
{
    const int n = blockIdx.x * 64 + threadIdx.x;   // [0,4096)

    // LN1 closed-form stats
    float av[kCH], dvv[kCH], g1[kCH], b1[kCH];
    float mw = 0.f, mb = 0.f;
    #pragma unroll
    for (int c = 0; c < kCH; ++c) {
        av[c] = w_in[c]; dvv[c] = b_in[c];
        g1[c] = ln1_g[c]; b1[c] = ln1_b[c];
        mw += av[c]; mb += dvv[c];
    }
    mw *= (1.f / kCH); mb *= (1.f / kCH);
    float Saa = 0.f, Sad = 0.f, Sdd = 0.f;
    #pragma unroll
    for (int c = 0; c < kCH; ++c) {
        av[c] -= mw; dvv[c] -= mb;
        Saa += av[c] * av[c];
        Sad += av[c] * dvv[c];
        Sdd += dvv[c] * dvv[c];
    }
    Saa *= (1.f / kCH); Sad *= (1.f / kCH); Sdd *= (1.f / kCH);

    // per-pole discretization + projected input vectors
    float Lbr[kP], Lbi[kP];
    float P1r[kP], P1i[kP], P0r[kP], P0i[kP], Pbr[kP], Pbi[kP];
    float msk[kP];
    #pragma unroll
    for (int p = 0; p < kP; ++p) {
        float st  = expf(log_step[p]);
        float lre = Lam_re[p], lim = Lam_im[p];
        float eL  = expf(lre * st);
        float lbr = eL * cosf(lim * st), lbi = eL * sinf(lim * st);
        Lbr[p] = lbr; Lbi[p] = lbi;
        float inv = 1.f / (lre * lre + lim * lim);
        float nr = lbr - 1.f, ni = lbi;
        float qr = (nr * lre + ni * lim) * inv;    // (Lam_bar-1)/Lam
        float qi = (ni * lre - nr * lim) * inv;
        float s1r = 0.f, s1i = 0.f, s0r = 0.f, s0i = 0.f, sbr = 0.f, sbi = 0.f;
        #pragma unroll
        for (int c = 0; c < kCH; ++c) {
            float br = Bre[p * kCH + c], bi = Bim[p * kCH + c];
            float a1 = av[c]  * g1[c];
            float a0 = dvv[c] * g1[c];
            s1r += a1 * br;   s1i += a1 * bi;
            s0r += a0 * br;   s0i += a0 * bi;
            sbr += b1[c] * br; sbi += b1[c] * bi;
        }
        P1r[p] = qr * s1r - qi * s1i;  P1i[p] = qr * s1i + qi * s1r;
        P0r[p] = qr * s0r - qi * s0i;  P0i[p] = qr * s0i + qi * s0r;
        Pbr[p] = qr * sbr - qi * sbi;  Pbi[p] = qr * sbi + qi * sbr;
        float freq = st * fabsf(lim) * 0.15915494309189535f;  // /(2*pi)
        msk[p] = (freq < 0.25f) ? 1.f : 0.f;
    }

    float xr[kP], xi[kP];
    #pragma unroll
    for (int p = 0; p < kP; ++p) { xr[p] = 0.f; xi[p] = 0.f; }

    float s_last = 0.f, r_last = 0.f;
    for (int t = 0; t < kT; ++t) {
        float s = seq[t * kN + n];
        float var = (s * s) * Saa + 2.f * s * Sad + Sdd;
        float r = rsqrtf(var + kEPS);
        float be = r * s;
        #pragma unroll
        for (int p = 0; p < kP; ++p) {
            float bur = be * P1r[p] + r * P0r[p] + Pbr[p];
            float bui = be * P1i[p] + r * P0i[p] + Pbi[p];
            float nxr = Lbr[p] * xr[p] - Lbi[p] * xi[p] + bur;
            float nxi = Lbr[p] * xi[p] + Lbi[p] * xr[p] + bui;
            xr[p] = nxr; xi[p] = nxi;
        }
        s_last = s; r_last = r;
    }

    // last-step head
    float fx[kCH];
    #pragma unroll
    for (int c = 0; c < kCH; ++c)
        fx[c] = (s_last * av[c] + dvv[c]) * r_last * g1[c] + b1[c];

    float xmr[kP], xmi[kP];
    #pragma unroll
    for (int p = 0; p < kP; ++p) { xmr[p] = xr[p] * msk[p]; xmi[p] = xi[p] * msk[p]; }

    float x1[kCH];
    float m1 = 0.f;
    #pragma unroll
    for (int c = 0; c < kCH; ++c) {
        float ys = fx[c] * Dv[c];
        #pragma unroll
        for (int p = 0; p < kP; ++p)
            ys += xmr[p] * Cre[c * kP + p] - xmi[p] * Cim[c * kP + p];
        x1[c] = gelu_exact(ys) + fx[c];
        m1 += x1[c];
    }
    m1 *= (1.f / kCH);
    float v1 = 0.f;
    #pragma unroll
    for (int c = 0; c < kCH; ++c) { float d = x1[c] - m1; v1 += d * d; }
    v1 *= (1.f / kCH);
    float rs2 = rsqrtf(v1 + kEPS);
    float fx2[kCH];
    #pragma unroll
    for (int c = 0; c < kCH; ++c)
        fx2[c] = (x1[c] - m1) * rs2 * ln2_g[c] + ln2_b[c];

    float hgate[kCH];
    #pragma unroll
    for (int j = 0; j < kCH; ++j) {
        float e1 = 0.f, e2 = 0.f;
        #pragma unroll
        for (int c = 0; c < kCH; ++c) {
            e1 += fx2[c] * w_enc[j * kCH + c];
            e2 += fx2[c] * w_enc[(kCH + j) * kCH + c];
        }
        hgate[j] = e1 * gelu_exact(e2);
    }
    float x2v[kCH];
    #pragma unroll
    for (int c = 0; c < kCH; ++c) {
        float acc = fx2[c];
        #pragma unroll
        for (int j = 0; j < kCH; ++j) acc += hgate[j] * w_dec[c * kCH + j];
        x2v[c] = acc;
    }
    int b = n >> 8, rem = n & 255;
    #pragma unroll
    for (int c = 0; c < kCH; ++c) {
        float acc = b_out[c];
        #pragma unroll
        for (int j = 0; j < kCH; ++j) acc += x2v[j] * w_out[c * kCH + j];
        yd[(b * kCH + c) * 256 + rem] = acc;   // yd[b][c][i][k] layout
    }
}

// ---------------------------------------------------------------------------
// K3: bilinear upsample 16x16 -> 480x640 per (b,ch). Grid (10 chunks, 256
// images): each block does 48 output rows = 7680 float4 = 30 stores/thread.
// 2560 blocks -> 10 blocks/CU, fully occupancy-capped. Source tile in LDS
// (reads are mostly wave-broadcast), float4 coalesced stores. Writes 315 MB.
// ---------------------------------------------------------------------------
__global__ __launch_bounds__(256) void k_up(const float* __restrict__ yd,
                                            float* __restrict__ out) {
    const int chunk = blockIdx.x;           // [0,10) -> rows [chunk*48, +48)
    const int bc    = blockIdx.y;           // b*16 + c
    __shared__ float g[256];                // 16x16 source tile
    g[threadIdx.x] = yd[bc * 256 + threadIdx.x];
    __syncthreads();
    float4* dst = (float4*)(out + (size_t)bc * (kH * kW));
    const float sy = 15.0f / 479.0f;
    const float sx = 15.0f / 639.0f;
    const int base = chunk * 7680;          // f4 index of this chunk's start
    #pragma unroll 2
    for (int it = 0; it < 30; ++it) {
        int local = it * 256 + (int)threadIdx.x;    // [0, 7680)
        int hol = local / 160;
        int w4  = local - hol * 160;
        int ho  = chunk * 48 + hol;
        float ry = (float)ho * sy;
        int y0 = (int)ry;
        float wy = ry - (float)y0;
        int y1 = min(y0 + 1, 15);
        const float* r0 = &g[y0 * 16];
        const float* r1 = &g[y1 * 16];
        float4 res;
        #pragma unroll
        for (int j = 0; j < 4; ++j) {
            int wo = w4 * 4 + j;
            float rx = (float)wo * sx;
            int x0 = (int)rx;
            float wx = rx - (float)x0;
            int x1 = min(x0 + 1, 15);
            float top = r0[x0] + (r0[x1] - r0[x0]) * wx;
            float bot = r1[x0] + (r1[x1] - r1[x0]) * wx;
            ((float*)&res)[j] = top + (bot - top) * wy;
        }
        dst[base + local] = res;
    }
}

extern "C" void kernel_launch(void* const* d_in, const int* in_sizes, int n_in,
                              void* d_out, int out_size, void* d_ws, size_t ws_size,
                              hipStream_t stream) {
    const float* x     = (const float*)d_in[0];
    const float* w_in  = (const float*)d_in[1];
    const float* b_in  = (const float*)d_in[2];
    const float* ln1_g = (const float*)d_in[3];
    const float* ln1_b = (const float*)d_in[4];
    const float* Lre   = (const float*)d_in[5];
    const float* Lim   = (const float*)d_in[6];
    const float* Bre   = (const float*)d_in[7];
    const float* Bim   = (const float*)d_in[8];
    const float* Cre   = (const float*)d_in[9];
    const float* Cim   = (const float*)d_in[10];
    const float* Dv    = (const float*)d_in[11];
    const float* lstep = (const float*)d_in[12];
    const float* ln2_g = (const float*)d_in[13];
    const float* ln2_b = (const float*)d_in[14];
    const float* w_enc = (const float*)d_in[15];
    const float* w_dec = (const float*)d_in[16];
    const float* w_out = (const float*)d_in[17];
    const float* b_out = (const float*)d_in[18];

    float* seq = (float*)d_ws;          // kT*kN      = 61440 floats
    float* yd  = seq + kT * kN;         // kB*kCH*256 = 65536 floats
    float* out = (float*)d_out;

    k_down<<<kB * kT * 16, 320, 0, stream>>>(x, seq);
    k_ssm<<<kN / 64, 64, 0, stream>>>(seq, w_in, b_in, ln1_g, ln1_b, Lre, Lim,
                                      Bre, Bim, Cre, Cim, Dv, lstep, ln2_g, ln2_b,
                                      w_enc, w_dec, w_out, b_out, yd);
    k_up<<<dim3(10, kB * kCH), 256, 0, stream>>>(yd, out);
}